// Round 10
// baseline (2501.193 us; speedup 1.0000x reference)
//
#include <hip/hip_runtime.h>
#include <hip/hip_bf16.h>

#define NROWS 8192
#define DIM   512
#define KNN   32
#define NPAIR 2048
#define NK    (DIM / 16)         // 32 K-steps (BK=16)

typedef __attribute__((ext_vector_type(8)))  short bf16x8;
typedef __attribute__((ext_vector_type(16))) float f32x16;

#define WAITV(N) asm volatile("s_waitcnt vmcnt(" #N ")" ::: "memory")
#define LGKM0()  asm volatile("s_waitcnt lgkmcnt(0)" ::: "memory")
#define RD(off)  (*(const bf16x8*)(smem + (off)))
#define MFMA(a, b, c) __builtin_amdgcn_mfma_f32_32x32x16_bf16((a), (b), (c), 0, 0, 0)

__device__ __forceinline__ void gload16(const void* g, void* l) {
    __builtin_amdgcn_global_load_lds(
        (const __attribute__((address_space(1))) void*)g,
        (__attribute__((address_space(3))) void*)l, 16, 0, 0);
}

__device__ __forceinline__ unsigned short bfrne(float x) {
    unsigned u = __float_as_uint(x);
    return (unsigned short)((u + 0x7FFFu + ((u >> 16) & 1u)) >> 16);
}

// ---------------- row squared norms ----------------
__global__ __launch_bounds__(256) void sqnorm_k(const float* __restrict__ E,
                                                float* __restrict__ sq) {
    int row  = blockIdx.x * 4 + (threadIdx.x >> 6);
    int lane = threadIdx.x & 63;
    const float4* e4 = reinterpret_cast<const float4*>(E + (size_t)row * DIM);
    float acc = 0.f;
#pragma unroll
    for (int t = 0; t < 2; ++t) {
        float4 v = e4[lane + 64 * t];
        acc += v.x * v.x + v.y * v.y + v.z * v.z + v.w * v.w;
    }
#pragma unroll
    for (int off = 32; off; off >>= 1) acc += __shfl_xor(acc, off);
    if (lane == 0) sq[row] = acc;
}

// ---------------- split fp32 -> bf16 hi/lo, packed in MFMA-fragment order ----
__global__ __launch_bounds__(256) void prep_k(const float* __restrict__ E,
                                              short* __restrict__ Phi,
                                              short* __restrict__ Plo) {
    const int p    = blockIdx.x * 256 + threadIdx.x;
    const int lane = p & 63;
    const int s    = (p >> 6) & 31;
    const int rb   = p >> 11;
    const int row  = rb * 32 + (lane & 31);
    const int k0   = s * 16 + (lane >> 5) * 8;
    const float4* src = reinterpret_cast<const float4*>(E + (size_t)row * DIM + k0);
    float4 x0 = src[0], x1 = src[1];
    float xs[8] = {x0.x, x0.y, x0.z, x0.w, x1.x, x1.y, x1.z, x1.w};
    short hs[8], ls[8];
#pragma unroll
    for (int e = 0; e < 8; ++e) {
        unsigned short hb = bfrne(xs[e]);
        float hf = __uint_as_float(((unsigned)hb) << 16);
        hs[e] = (short)hb;
        ls[e] = (short)bfrne(xs[e] - hf);
    }
    bf16x8 h, l;
#pragma unroll
    for (int e = 0; e < 8; ++e) { h[e] = hs[e]; l[e] = ls[e]; }
    *reinterpret_cast<bf16x8*>(Phi + (size_t)p * 8) = h;
    *reinterpret_cast<bf16x8*>(Plo + (size_t)p * 8) = l;
}

// ---------------- pure score-GEMM: scores = sq_j - 2*(hi.hi + hi.lo + lo.hi) --
// 512 thr, 8 waves (2rg x 4cg), tile 128x256, per-wave 64x64 (8 ds_read :
// 12 MFMA per BK=16 step). Double-buffered LDS 48KB -> 3 WGs/CU.
// Counted vmcnt(3) + raw s_barrier (m97/R8-verified engine, uninterrupted).
// XCD supertile swizzle: xcd = bid&7 owns r-tiles [xcd*rpx, ...) x all cols.
__global__ __launch_bounds__(512, 6) void gemm_k(const short* __restrict__ Phi,
                                                 const short* __restrict__ Plo,
                                                 const float* __restrict__ sq,
                                                 float* __restrict__ scores,
                                                 int r0_base, int nrt) {
    extern __shared__ char smem[];
    // A: [buf2][slot8: m*4+rb][512 shorts] = 16 KB @0
    // B: [buf2][slot16: m*8+cb][512 shorts] = 32 KB @16384
    const int tid  = threadIdx.x;
    const int w    = tid >> 6;
    const int lane = tid & 63;
    const int kh   = lane >> 5;
    const int c32  = lane & 31;
    const int rg   = w >> 2;
    const int cg   = w & 3;
    const int laneoff = lane * 16;

    const int rpx = nrt >> 3;                 // r-tiles per XCD
    const int xcd = blockIdx.x & 7;
    const int q   = blockIdx.x >> 3;
    const int tr  = xcd * rpx + (q % rpx);
    const int tc  = q / rpx;
    const int r0  = r0_base + tr * 128;
    const int c0  = tc * 256;

    const int mat = w >> 2;                   // waves 0-3 stage hi, 4-7 lo
    const short* __restrict__ Pm = mat ? Plo : Phi;

    const short* pA  = Pm + (size_t)((r0 >> 5) + (w & 3)) * 16384 + lane * 8;
    const short* pB0 = Pm + (size_t)((c0 >> 5) + ((2 * w) & 7)) * 16384 + lane * 8;
    const short* pB1 = pB0 + 16384;
    const int dstA = w * 1024;                                  // + buf*8192
    const int dstB = 16384 + (mat * 8 + ((2 * w) & 7)) * 1024;  // + buf*16384

    f32x16 acc[2][2];
#pragma unroll
    for (int rbs = 0; rbs < 2; ++rbs)
#pragma unroll
        for (int ci = 0; ci < 2; ++ci)
#pragma unroll
            for (int m = 0; m < 16; ++m) acc[rbs][ci][m] = 0.f;

    // prologue: stage step 0 into buf 0
    gload16(pA,  smem + dstA);
    gload16(pB0, smem + dstB);
    gload16(pB1, smem + dstB + 1024);
    pA += 512; pB0 += 512; pB1 += 512;

#define STEP(T, BUF)                                                           \
    {                                                                          \
        if ((T) + 1 < NK) {                                                    \
            gload16(pA,  smem + (((BUF) ^ 1) * 8192)  + dstA);                 \
            gload16(pB0, smem + (((BUF) ^ 1) * 16384) + dstB);                 \
            gload16(pB1, smem + (((BUF) ^ 1) * 16384) + dstB + 1024);          \
            pA += 512; pB0 += 512; pB1 += 512;                                 \
            WAITV(3);                                                          \
        } else {                                                               \
            WAITV(0);                                                          \
        }                                                                      \
        __builtin_amdgcn_s_barrier();                                          \
        __builtin_amdgcn_sched_barrier(0);                                     \
        const int aoff = (BUF) * 8192 + rg * 2048 + laneoff;                   \
        const int boff = 16384 + (BUF) * 16384 + cg * 2048 + laneoff;          \
        bf16x8 ah0 = RD(aoff),        ah1 = RD(aoff + 1024);                   \
        bf16x8 al0 = RD(aoff + 4096), al1 = RD(aoff + 5120);                   \
        bf16x8 bh0 = RD(boff),        bh1 = RD(boff + 1024);                   \
        bf16x8 bl0 = RD(boff + 8192), bl1 = RD(boff + 9216);                   \
        acc[0][0] = MFMA(ah0, bh0, acc[0][0]);                                 \
        acc[0][0] = MFMA(ah0, bl0, acc[0][0]);                                 \
        acc[0][0] = MFMA(al0, bh0, acc[0][0]);                                 \
        acc[0][1] = MFMA(ah0, bh1, acc[0][1]);                                 \
        acc[0][1] = MFMA(ah0, bl1, acc[0][1]);                                 \
        acc[0][1] = MFMA(al0, bh1, acc[0][1]);                                 \
        acc[1][0] = MFMA(ah1, bh0, acc[1][0]);                                 \
        acc[1][0] = MFMA(ah1, bl0, acc[1][0]);                                 \
        acc[1][0] = MFMA(al1, bh0, acc[1][0]);                                 \
        acc[1][1] = MFMA(ah1, bh1, acc[1][1]);                                 \
        acc[1][1] = MFMA(ah1, bl1, acc[1][1]);                                 \
        acc[1][1] = MFMA(al1, bh1, acc[1][1]);                                 \
        LGKM0();                                                               \
        __builtin_amdgcn_s_barrier();                                          \
        __builtin_amdgcn_sched_barrier(0);                                     \
    }

    for (int tt = 0; tt < NK; tt += 2) {
        STEP(tt, 0)
        STEP(tt + 1, 1)
    }
#undef STEP

    // epilogue: scores[row_local][col] = sq[col] - 2*acc  (R4-verified mapping)
    const float sqv0 = sq[c0 + cg * 64 + c32];
    const float sqv1 = sq[c0 + cg * 64 + 32 + c32];
    float* srow = scores + (size_t)(r0 - r0_base + rg * 64) * NROWS + c0 + cg * 64;
#pragma unroll
    for (int rbs = 0; rbs < 2; ++rbs)
#pragma unroll
        for (int ci = 0; ci < 2; ++ci) {
            const float sv = ci ? sqv1 : sqv0;
#pragma unroll
            for (int m = 0; m < 16; ++m) {
                const int sub = (m & 3) + 8 * (m >> 2) + 4 * kh;
                srow[(size_t)(rbs * 32 + sub) * NROWS + ci * 32 + c32] =
                    sv - 2.f * acc[rbs][ci][m];
            }
        }
}

// ---------------- streaming top-33 per row -> knn (drop rank 0 = self) ------
// 4 waves/WG, 1 row/wave. Coalesced float4 row reads in 32 blocks of 256
// cols (full row coverage); verified warm-started wave-sorted insertion
// (sorted list in lanes 0..32, tie-break smaller idx).
__global__ __launch_bounds__(256) void select_k(const float* __restrict__ scores,
                                                int* __restrict__ knn,
                                                int r0_base) {
    const int w    = threadIdx.x >> 6;
    const int lane = threadIdx.x & 63;
    const int lrow = blockIdx.x * 4 + w;
    const int grow = r0_base + lrow;
    const float* __restrict__ S = scores + (size_t)lrow * NROWS;
    const float INF_F = __builtin_inff();

    float tv = INF_F; int ti = -1;
    for (int blk = 0; blk < NROWS / 256; ++blk) {
        const float4 f = *(const float4*)(S + blk * 256 + 4 * lane);
        float mn = fminf(fminf(f.x, f.y), fminf(f.z, f.w));
        float t0e = INF_F;
        if (blk == 0) {
            // bitonic-sort the 64 per-lane mins; 33rd smallest is a valid
            // upper bound on the block's true 33rd smallest.
            float v = mn;
#pragma unroll
            for (int k = 2; k <= 64; k <<= 1)
#pragma unroll
                for (int j = k >> 1; j; j >>= 1) {
                    float o = __shfl_xor(v, j);
                    const bool lower = ((lane & j) == 0);
                    const bool dir   = ((lane & k) == 0);
                    v = (lower == dir) ? fminf(v, o) : fmaxf(v, o);
                }
            float t0 = __shfl(v, 32);
            t0e = t0 + fabsf(t0) * 1e-6f + 1e-30f;   // nudge up
        }
        float lthr = __shfl(tv, 32);
        float gate = fminf(lthr, t0e);
        while (true) {
            unsigned long long bal = __ballot(mn < gate);
            if (!bal) break;
            const int src = (int)__builtin_ctzll(bal);
            const float gx = __shfl(f.x, src);
            const float gy = __shfl(f.y, src);
            const float gz = __shfl(f.z, src);
            const float gw = __shfl(f.w, src);
            const int jc0 = blk * 256 + 4 * src;
            if (lane == src) mn = INF_F;
#define INS(VV, JJ)                                                         \
            if ((VV) < gate) {                                              \
                float pv = __shfl_up(tv, 1);                                \
                int   pi = __shfl_up(ti, 1);                                \
                if (lane == 0) pv = -INF_F;                                 \
                if (tv > (VV)) {                                            \
                    const bool tk = pv > (VV);                              \
                    tv = tk ? pv : (VV);                                    \
                    ti = tk ? pi : (JJ);                                    \
                }                                                           \
                lthr = __shfl(tv, 32);                                      \
                gate = fminf(lthr, t0e);                                    \
            }
            INS(gx, jc0); INS(gy, jc0 + 1); INS(gz, jc0 + 2); INS(gw, jc0 + 3);
#undef INS
        }
    }
    // lanes 1..32 hold ranks 1..32 (rank 0 = self: s_ii = -sq_i is row min)
    if (lane >= 1 && lane <= 32)
        knn[(size_t)grow * KNN + lane - 1] = ti;
}

// ---------------- overlap + rank + per-pair partial loss ----------------
__global__ __launch_bounds__(64) void overlap_k(const int* __restrict__ knn,
                                                const int* __restrict__ pairs,
                                                const float* __restrict__ refso,
                                                float* __restrict__ partial) {
    const int p    = blockIdx.x;
    const int lane = threadIdx.x;
    __shared__ int si[KNN];
    const int i = pairs[p];
    if (lane < KNN) si[lane] = knn[(size_t)i * KNN + lane];
    __syncthreads();

    float v = 0.f;
    if (lane < KNN) {
        const int j = si[lane];
        int t[KNN];
        const int4* kj = reinterpret_cast<const int4*>(knn + (size_t)j * KNN);
#pragma unroll
        for (int b = 0; b < KNN / 4; ++b) {
            int4 q = kj[b];
            t[4 * b + 0] = q.x; t[4 * b + 1] = q.y;
            t[4 * b + 2] = q.z; t[4 * b + 3] = q.w;
        }
        int cnt = 0;
        for (int a = 0; a < KNN; ++a) {
            int sa = si[a];
#pragma unroll
            for (int b = 0; b < KNN; ++b) cnt += (t[b] == sa);
        }
        v = (float)cnt * (1.0f / KNN);
    }
    int rank = 0;
    for (int q = 0; q < KNN; ++q) {
        float ov = __shfl(v, q);
        rank += (lane < KNN) && ((ov < v) || (ov == v && q < lane));
    }
    float err = 0.f;
    if (lane < KNN) {
        float r = refso[(size_t)p * KNN + rank];
        float d = v - r;
        err = d * d;
    }
#pragma unroll
    for (int off = 32; off; off >>= 1) err += __shfl_xor(err, off);
    if (lane == 0) partial[p] = err;
}

// ---------------- deterministic final reduce ----------------
__global__ __launch_bounds__(256) void final_k(const float* __restrict__ partial,
                                               float* __restrict__ out) {
    const int tid = threadIdx.x;
    float a = 0.f;
    for (int q = tid; q < NPAIR; q += 256) a += partial[q];
#pragma unroll
    for (int off = 32; off; off >>= 1) a += __shfl_xor(a, off);
    __shared__ float red[4];
    if ((tid & 63) == 0) red[tid >> 6] = a;
    __syncthreads();
    if (tid == 0)
        out[0] = (red[0] + red[1] + red[2] + red[3]) * (1.0f / (NPAIR * KNN));
}

// ================= round-1 fallback (used only if ws too small) =================
__global__ __launch_bounds__(256) void dist_topk_k(const float* __restrict__ E,
                                                   const float* __restrict__ sq,
                                                   int* __restrict__ knn) {
    extern __shared__ float sc[];
    const int tid = threadIdx.x;
    const int r0  = blockIdx.x * 4;
    const float4* a0 = reinterpret_cast<const float4*>(E + (size_t)(r0 + 0) * DIM);
    const float4* a1 = reinterpret_cast<const float4*>(E + (size_t)(r0 + 1) * DIM);
    const float4* a2 = reinterpret_cast<const float4*>(E + (size_t)(r0 + 2) * DIM);
    const float4* a3 = reinterpret_cast<const float4*>(E + (size_t)(r0 + 3) * DIM);
    for (int tile = 0; tile < NROWS / 256; ++tile) {
        int j = tile * 256 + tid;
        const float4* bj = reinterpret_cast<const float4*>(E + (size_t)j * DIM);
        float acc0 = 0.f, acc1 = 0.f, acc2 = 0.f, acc3 = 0.f;
#pragma unroll 4
        for (int dd = 0; dd < DIM / 4; ++dd) {
            float4 b  = bj[dd];
            float4 x0 = a0[dd], x1 = a1[dd], x2 = a2[dd], x3 = a3[dd];
            acc0 += x0.x * b.x + x0.y * b.y + x0.z * b.z + x0.w * b.w;
            acc1 += x1.x * b.x + x1.y * b.y + x1.z * b.z + x1.w * b.w;
            acc2 += x2.x * b.x + x2.y * b.y + x2.z * b.z + x2.w * b.w;
            acc3 += x3.x * b.x + x3.y * b.y + x3.z * b.z + x3.w * b.w;
        }
        float sj = sq[j];
        sc[0 * NROWS + j] = sj - 2.f * acc0;
        sc[1 * NROWS + j] = sj - 2.f * acc1;
        sc[2 * NROWS + j] = sj - 2.f * acc2;
        sc[3 * NROWS + j] = sj - 2.f * acc3;
    }
    __syncthreads();
    const int w    = tid >> 6;
    const int lane = tid & 63;
    float* s = sc + w * NROWS;
    const float INF = __builtin_inff();
    float m[4]; int mi[4];
#pragma unroll
    for (int b = 0; b < 4; ++b) {
        float bm = INF; int bmi = NROWS;
        for (int t = 0; t < 32; ++t) {
            int j = lane + 64 * (b * 32 + t);
            float v = s[j];
            if (v < bm || (v == bm && j < bmi)) { bm = v; bmi = j; }
        }
        m[b] = bm; mi[b] = bmi;
    }
    const int row = r0 + w;
    for (int it = 0; it < KNN + 1; ++it) {
        float cvv = m[0]; int cii = mi[0];
#pragma unroll
        for (int b = 1; b < 4; ++b)
            if (m[b] < cvv || (m[b] == cvv && mi[b] < cii)) { cvv = m[b]; cii = mi[b]; }
        float bv = cvv; int bi = cii;
#pragma unroll
        for (int off = 32; off; off >>= 1) {
            float ov = __shfl_xor(bv, off);
            int   oi = __shfl_xor(bi, off);
            if (ov < bv || (ov == bv && oi < bi)) { bv = ov; bi = oi; }
        }
        if (it > 0 && lane == 0) knn[(size_t)row * KNN + (it - 1)] = bi;
        int ol = bi & 63;
        if (lane == ol) {
            s[bi] = INF;
            int b = (bi >> 6) >> 5;
            float bm = INF; int bmi = NROWS;
            for (int t = 0; t < 32; ++t) {
                int j = lane + 64 * (b * 32 + t);
                float v = s[j];
                if (v < bm || (v == bm && j < bmi)) { bm = v; bmi = j; }
            }
            m[b] = bm; mi[b] = bmi;
        }
    }
}

extern "C" void kernel_launch(void* const* d_in, const int* in_sizes, int n_in,
                              void* d_out, int out_size, void* d_ws, size_t ws_size,
                              hipStream_t stream) {
    const float* E     = (const float*)d_in[0];
    const float* refso = (const float*)d_in[1];
    const int*   pairs = (const int*)d_in[2];
    float* out = (float*)d_out;

    char* ws = (char*)d_ws;
    float* sq      = (float*)ws;                         // 32 KB
    float* partial = (float*)(ws + 32768);               // 8 KB
    int*   knn     = (int*)(ws + 40960);                 // 1 MB
    short* Phi     = (short*)(ws + 1089536);             // 8 MB packed hi
    short* Plo     = (short*)(ws + 9478144);             // 8 MB packed lo
    float* scores  = (float*)(ws + 17866752);            // up to 256 MB
    const size_t BASE      = 17866752;
    const size_t NEED_FULL = BASE + (size_t)NROWS * NROWS * 4;       // 286.3 MB
    const size_t NEED_BAND = BASE + (size_t)2048 * NROWS * 4;        // 85.0 MB

    if (ws_size >= NEED_BAND) {
        hipFuncSetAttribute((const void*)gemm_k,
                            hipFuncAttributeMaxDynamicSharedMemorySize, 49152);
        sqnorm_k<<<NROWS / 4, 256, 0, stream>>>(E, sq);
        prep_k<<<NROWS * DIM / 8 / 256, 256, 0, stream>>>(E, Phi, Plo);
        if (ws_size >= NEED_FULL) {
            gemm_k<<<2048, 512, 49152, stream>>>(Phi, Plo, sq, scores, 0, 64);
            select_k<<<NROWS / 4, 256, 0, stream>>>(scores, knn, 0);
        } else {
            for (int b = 0; b < 4; ++b) {
                gemm_k<<<512, 512, 49152, stream>>>(Phi, Plo, sq, scores, b * 2048, 16);
                select_k<<<512, 256, 0, stream>>>(scores, knn, b * 2048);
            }
        }
    } else {
        hipFuncSetAttribute((const void*)dist_topk_k,
                            hipFuncAttributeMaxDynamicSharedMemorySize, 131072);
        sqnorm_k<<<NROWS / 4, 256, 0, stream>>>(E, sq);
        dist_topk_k<<<NROWS / 4, 256, 131072, stream>>>(E, sq, knn);
    }
    overlap_k<<<NPAIR, 64, 0, stream>>>(knn, pairs, refso, partial);
    final_k<<<1, 256, 0, stream>>>(partial, out);
}

// Round 11
// 803.674 us; speedup vs baseline: 3.1122x; 3.1122x over previous
//
#include <hip/hip_runtime.h>
#include <hip/hip_bf16.h>

#define NROWS 8192
#define DIM   512
#define KNN   32
#define NPAIR 2048

#define STRIPS 8
#define SCOLS  1024   // cols per strip: 2MB hi+lo -> L2-resident per XCD
#define CHUNK  256    // cols per selection chunk
#define BK     32     // K-step
#define MROWS  64     // rows per WG
#define NSTEP  ((SCOLS / CHUNK) * (DIM / BK))   // 4 * 16 = 64
#define NCAND  (STRIPS * 33)                    // 264

typedef __attribute__((ext_vector_type(8)))  short bf16x8;
typedef __attribute__((ext_vector_type(16))) float f32x16;

__device__ __forceinline__ void gload16(const void* g, void* l) {
    __builtin_amdgcn_global_load_lds(
        (const __attribute__((address_space(1))) void*)g,
        (__attribute__((address_space(3))) void*)l, 16, 0, 0);
}

__device__ __forceinline__ unsigned short bfrne(float x) {
    unsigned u = __float_as_uint(x);
    return (unsigned short)((u + 0x7FFFu + ((u >> 16) & 1u)) >> 16);
}

// ---------------- row squared norms ----------------
__global__ __launch_bounds__(256) void sqnorm_k(const float* __restrict__ E,
                                                float* __restrict__ sq) {
    int row  = blockIdx.x * 4 + (threadIdx.x >> 6);
    int lane = threadIdx.x & 63;
    const float4* e4 = reinterpret_cast<const float4*>(E + (size_t)row * DIM);
    float acc = 0.f;
#pragma unroll
    for (int t = 0; t < 2; ++t) {
        float4 v = e4[lane + 64 * t];
        acc += v.x * v.x + v.y * v.y + v.z * v.z + v.w * v.w;
    }
#pragma unroll
    for (int off = 32; off; off >>= 1) acc += __shfl_xor(acc, off);
    if (lane == 0) sq[row] = acc;
}

// ---------------- split fp32 -> bf16 hi/lo, packed in MFMA-fragment order ----
// Packet p = ((rb32*32 + s)*64 + lane): row = rb32*32 + (lane&31),
// k = s*16 + (lane>>5)*8 + e.
__global__ __launch_bounds__(256) void prep_k(const float* __restrict__ E,
                                              short* __restrict__ Phi,
                                              short* __restrict__ Plo) {
    const int p    = blockIdx.x * 256 + threadIdx.x;
    const int lane = p & 63;
    const int s    = (p >> 6) & 31;
    const int rb   = p >> 11;
    const int row  = rb * 32 + (lane & 31);
    const int k0   = s * 16 + (lane >> 5) * 8;
    const float4* src = reinterpret_cast<const float4*>(E + (size_t)row * DIM + k0);
    float4 x0 = src[0], x1 = src[1];
    float xs[8] = {x0.x, x0.y, x0.z, x0.w, x1.x, x1.y, x1.z, x1.w};
    short hs[8], ls[8];
#pragma unroll
    for (int e = 0; e < 8; ++e) {
        unsigned short hb = bfrne(xs[e]);
        float hf = __uint_as_float(((unsigned)hb) << 16);
        hs[e] = (short)hb;
        ls[e] = (short)bfrne(xs[e] - hf);
    }
    bf16x8 h, l;
#pragma unroll
    for (int e = 0; e < 8; ++e) { h[e] = hs[e]; l[e] = ls[e]; }
    *reinterpret_cast<bf16x8*>(Phi + (size_t)p * 8) = h;
    *reinterpret_cast<bf16x8*>(Plo + (size_t)p * 8) = l;
}

// ---------------- fused distance-GEMM + strip top-33 (R5 structure) ---------
// 512 threads (8 waves). WG tile 64x256, per-wave 32x64 (acc[2] of 32x32).
// Single-buffered stage -> __syncthreads -> compute (R5's proven loop).
// strips=8: B strip 2MB = L2-resident per XCD (st = bid&7). SC shrunk to
// [8][256] (8 KB): selection in 8 phases of 1 row/wave. LDS 48 KB ->
// 3 WGs/CU. SoA emit cval[st][row][33] (same-XCD-only writes).
__global__ __launch_bounds__(512, 6) void distsel_k(const short* __restrict__ Phi,
                                                    const short* __restrict__ Plo,
                                                    const float* __restrict__ sq,
                                                    float* __restrict__ cval,
                                                    int* __restrict__ cidx) {
    extern __shared__ char smem[];
    // At: [mat2][rb2][s2][512 shorts]  =  8 KB
    // Bt: [mat2][cb8][s2][512 shorts]  = 32 KB
    // SC: [8][256] f32                 =  8 KB   (total 48 KB)
    short* At = (short*)smem;
    short* Bt = (short*)(smem + 8192);
    float* SC = (float*)(smem + 40960);

    const int tid  = threadIdx.x;
    const int w    = tid >> 6;
    const int lane = tid & 63;
    const int kh   = lane >> 5;
    const int c32  = lane & 31;
    const int rbk  = blockIdx.x >> 3;
    const int st   = blockIdx.x & 7;
    const int r0   = rbk * MROWS;
    const int cstrip = st * SCOLS;
    const float INF_F = __builtin_inff();

    const int rb  = w >> 2;          // wave's rowblock (0..1)
    const int cb0 = 2 * (w & 3);     // wave's first colblock (0,2,4,6)

    // stage k-step t into the single buffers: 5 gload16 per wave
    auto stage = [&](int t) {
        const int ch = t >> 4, ksg = t & 15;
        {   // A slot q = w: (mat, rb, s)
            const int m = w >> 2, rbL = (w >> 1) & 1, s = w & 1;
            const short* Pm = m ? Plo : Phi;
            const size_t pk = ((size_t)(((r0 >> 5) + rbL) * 32 + 2 * ksg + s) * 64 + lane) * 8;
            gload16(Pm + pk, At + (((m * 2 + rbL) * 2 + s) * 512));
        }
#pragma unroll
        for (int j = 0; j < 4; ++j) {   // B slots q = 4w+j: (mat, cb, s)
            const int q = 4 * w + j;
            const int m = q >> 4, cbL = (q >> 1) & 7, s = q & 1;
            const short* Pm = m ? Plo : Phi;
            const size_t pk = ((size_t)(((cstrip >> 5) + ch * 8 + cbL) * 32 + 2 * ksg + s) * 64 + lane) * 8;
            gload16(Pm + pk, Bt + (((m * 8 + cbL) * 2 + s) * 512));
        }
    };

    // selection state: 8 rows per wave; slot q -> row r0 + 32*(q>>2) + 8*(q&3) + w
    float Tv[8]; int Ti[8];
#pragma unroll
    for (int r = 0; r < 8; ++r) { Tv[r] = INF_F; Ti[r] = -1; }

    f32x16 acc[2];
#pragma unroll
    for (int ci = 0; ci < 2; ++ci)
#pragma unroll
        for (int m = 0; m < 16; ++m) acc[ci][m] = 0.f;

    for (int t = 0; t < NSTEP; ++t) {
        stage(t);
        __syncthreads();   // vmcnt drained -> staged data visible

#pragma unroll
        for (int s = 0; s < 2; ++s) {
            const bf16x8 ah = *(const bf16x8*)(At + (((0 * 2 + rb) * 2 + s) * 512) + lane * 8);
            const bf16x8 al = *(const bf16x8*)(At + (((1 * 2 + rb) * 2 + s) * 512) + lane * 8);
#pragma unroll
            for (int ci = 0; ci < 2; ++ci) {
                const bf16x8 bh = *(const bf16x8*)(Bt + (((0 * 8 + cb0 + ci) * 2 + s) * 512) + lane * 8);
                const bf16x8 bl = *(const bf16x8*)(Bt + (((1 * 8 + cb0 + ci) * 2 + s) * 512) + lane * 8);
                acc[ci] = __builtin_amdgcn_mfma_f32_32x32x16_bf16(ah, bh, acc[ci], 0, 0, 0);
                acc[ci] = __builtin_amdgcn_mfma_f32_32x32x16_bf16(ah, bl, acc[ci], 0, 0, 0);
                acc[ci] = __builtin_amdgcn_mfma_f32_32x32x16_bf16(al, bh, acc[ci], 0, 0, 0);
            }
        }

        if ((t & 15) != 15) {
            __syncthreads();   // compute done -> buffers free for next stage
        } else {
            // -------- chunk done: 8 phases of (write 8 rows -> select 1/wave)
            const int ch = t >> 4;
            const int c0 = cstrip + ch * CHUNK;
            const float sqv0 = sq[c0 + (cb0 + 0) * 32 + c32];
            const float sqv1 = sq[c0 + (cb0 + 1) * 32 + c32];
#pragma unroll
            for (int q = 0; q < 8; ++q) {
                // phase q = WG-rows 32*(q>>2) + 8*(q&3) + [0,8): acc m in [4j,4j+4)
                if (rb == (q >> 2)) {
                    const int j = q & 3;
#pragma unroll
                    for (int ci = 0; ci < 2; ++ci) {
                        const float sv = ci ? sqv1 : sqv0;
#pragma unroll
                        for (int mm = 0; mm < 4; ++mm) {
                            const int m = 4 * j + mm;
                            SC[(mm + 4 * kh) * CHUNK + (cb0 + ci) * 32 + c32] =
                                sv - 2.f * acc[ci][m];
                        }
                    }
                }
                __syncthreads();
                {
                    float& tv = Tv[q];
                    int&   ti = Ti[q];
                    const float4 f = *(const float4*)(SC + w * CHUNK + 4 * lane);
                    float mn = fminf(fminf(f.x, f.y), fminf(f.z, f.w));
                    float t0e = INF_F;
                    if (ch == 0) {
                        // bitonic-sort the 64 per-lane mins; 33rd smallest is a
                        // valid upper bound on the chunk's true 33rd smallest.
                        float v = mn;
#pragma unroll
                        for (int k = 2; k <= 64; k <<= 1)
#pragma unroll
                            for (int jj = k >> 1; jj; jj >>= 1) {
                                float o = __shfl_xor(v, jj);
                                const bool lower = ((lane & jj) == 0);
                                const bool dir   = ((lane & k) == 0);
                                v = (lower == dir) ? fminf(v, o) : fmaxf(v, o);
                            }
                        float t0 = __shfl(v, 32);
                        t0e = t0 + fabsf(t0) * 1e-6f + 1e-30f;   // nudge up
                    }
                    float lthr = __shfl(tv, 32);
                    float gate = fminf(lthr, t0e);
                    while (true) {
                        unsigned long long bal = __ballot(mn < gate);
                        if (!bal) break;
                        const int src = (int)__builtin_ctzll(bal);
                        const float gx = __shfl(f.x, src);
                        const float gy = __shfl(f.y, src);
                        const float gz = __shfl(f.z, src);
                        const float gw = __shfl(f.w, src);
                        const int jc0 = c0 + 4 * src;
                        if (lane == src) mn = INF_F;
#define INS(VV, JJ)                                                         \
                        if ((VV) < gate) {                                  \
                            float pv = __shfl_up(tv, 1);                    \
                            int   pi = __shfl_up(ti, 1);                    \
                            if (lane == 0) pv = -INF_F;                     \
                            if (tv > (VV)) {                                \
                                const bool tk = pv > (VV);                  \
                                tv = tk ? pv : (VV);                        \
                                ti = tk ? pi : (JJ);                        \
                            }                                               \
                            lthr = __shfl(tv, 32);                          \
                            gate = fminf(lthr, t0e);                        \
                        }
                        INS(gx, jc0); INS(gy, jc0 + 1); INS(gz, jc0 + 2); INS(gw, jc0 + 3);
#undef INS
                    }
                }
                __syncthreads();
            }
            // reset accumulators for next chunk
#pragma unroll
            for (int ci = 0; ci < 2; ++ci)
#pragma unroll
                for (int m = 0; m < 16; ++m) acc[ci][m] = 0.f;
        }
    }

    // SoA emit: cval[st][row][33] — each strip plane written only by its XCD
#pragma unroll
    for (int q = 0; q < 8; ++q) {
        const int grow = r0 + 32 * (q >> 2) + 8 * (q & 3) + w;
        if (lane <= 32) {
            cval[(size_t)st * (NROWS * 33) + (size_t)grow * 33 + lane] = Tv[q];
            cidx[(size_t)st * (NROWS * 33) + (size_t)grow * 33 + lane] = Ti[q];
        }
    }
}

// ---------------- merge strips: global top-33 of 264 (SoA), drop self -------
__global__ __launch_bounds__(256) void merge_k(const float* __restrict__ cval,
                                               const int* __restrict__ cidx,
                                               int* __restrict__ knn) {
    const int row  = blockIdx.x * 4 + (threadIdx.x >> 6);
    const int lane = threadIdx.x & 63;
    const float INF_F = __builtin_inff();
    float vv[5]; int ii[5];
#pragma unroll
    for (int k = 0; k < 5; ++k) {
        const int idx = lane + 64 * k;
        const bool ok = idx < NCAND;
        const int stt = idx / 33;
        const int e   = idx - 33 * stt;
        const size_t off = (size_t)stt * (NROWS * 33) + (size_t)row * 33 + e;
        vv[k] = ok ? cval[off] : INF_F;
        ii[k] = ok ? cidx[off] : 0x7FFFFFFF;
    }
    for (int it = 0; it < 33; ++it) {
        float mv = vv[0]; int mi = ii[0]; int ms = 0;
#pragma unroll
        for (int k = 1; k < 5; ++k)
            if (vv[k] < mv || (vv[k] == mv && ii[k] < mi)) { mv = vv[k]; mi = ii[k]; ms = k; }
        float bv = mv; int bi = mi; int bl = lane;
#pragma unroll
        for (int off = 32; off; off >>= 1) {
            float ov = __shfl_xor(bv, off);
            int   oi = __shfl_xor(bi, off);
            int   ol = __shfl_xor(bl, off);
            if (ov < bv || (ov == bv && oi < bi)) { bv = ov; bi = oi; bl = ol; }
        }
        if (it > 0 && lane == 0) knn[(size_t)row * KNN + it - 1] = bi;
        if (lane == bl) {
#pragma unroll
            for (int k = 0; k < 5; ++k)
                if (k == ms) vv[k] = INF_F;
        }
    }
}

// ---------------- overlap + rank + per-pair partial loss ----------------
__global__ __launch_bounds__(64) void overlap_k(const int* __restrict__ knn,
                                                const int* __restrict__ pairs,
                                                const float* __restrict__ refso,
                                                float* __restrict__ partial) {
    const int p    = blockIdx.x;
    const int lane = threadIdx.x;
    __shared__ int si[KNN];
    const int i = pairs[p];
    if (lane < KNN) si[lane] = knn[(size_t)i * KNN + lane];
    __syncthreads();

    float v = 0.f;
    if (lane < KNN) {
        const int j = si[lane];
        int t[KNN];
        const int4* kj = reinterpret_cast<const int4*>(knn + (size_t)j * KNN);
#pragma unroll
        for (int b = 0; b < KNN / 4; ++b) {
            int4 q = kj[b];
            t[4 * b + 0] = q.x; t[4 * b + 1] = q.y;
            t[4 * b + 2] = q.z; t[4 * b + 3] = q.w;
        }
        int cnt = 0;
        for (int a = 0; a < KNN; ++a) {
            int sa = si[a];
#pragma unroll
            for (int b = 0; b < KNN; ++b) cnt += (t[b] == sa);
        }
        v = (float)cnt * (1.0f / KNN);
    }
    int rank = 0;
    for (int q = 0; q < KNN; ++q) {
        float ov = __shfl(v, q);
        rank += (lane < KNN) && ((ov < v) || (ov == v && q < lane));
    }
    float err = 0.f;
    if (lane < KNN) {
        float r = refso[(size_t)p * KNN + rank];
        float d = v - r;
        err = d * d;
    }
#pragma unroll
    for (int off = 32; off; off >>= 1) err += __shfl_xor(err, off);
    if (lane == 0) partial[p] = err;
}

// ---------------- deterministic final reduce ----------------
__global__ __launch_bounds__(256) void final_k(const float* __restrict__ partial,
                                               float* __restrict__ out) {
    const int tid = threadIdx.x;
    float a = 0.f;
    for (int q = tid; q < NPAIR; q += 256) a += partial[q];
#pragma unroll
    for (int off = 32; off; off >>= 1) a += __shfl_xor(a, off);
    __shared__ float red[4];
    if ((tid & 63) == 0) red[tid >> 6] = a;
    __syncthreads();
    if (tid == 0)
        out[0] = (red[0] + red[1] + red[2] + red[3]) * (1.0f / (NPAIR * KNN));
}

// ================= round-1 fallback (used only if ws too small) =================
__global__ __launch_bounds__(256) void dist_topk_k(const float* __restrict__ E,
                                                   const float* __restrict__ sq,
                                                   int* __restrict__ knn) {
    extern __shared__ float sc[];
    const int tid = threadIdx.x;
    const int r0  = blockIdx.x * 4;
    const float4* a0 = reinterpret_cast<const float4*>(E + (size_t)(r0 + 0) * DIM);
    const float4* a1 = reinterpret_cast<const float4*>(E + (size_t)(r0 + 1) * DIM);
    const float4* a2 = reinterpret_cast<const float4*>(E + (size_t)(r0 + 2) * DIM);
    const float4* a3 = reinterpret_cast<const float4*>(E + (size_t)(r0 + 3) * DIM);
    for (int tile = 0; tile < NROWS / 256; ++tile) {
        int j = tile * 256 + tid;
        const float4* bj = reinterpret_cast<const float4*>(E + (size_t)j * DIM);
        float acc0 = 0.f, acc1 = 0.f, acc2 = 0.f, acc3 = 0.f;
#pragma unroll 4
        for (int dd = 0; dd < DIM / 4; ++dd) {
            float4 b  = bj[dd];
            float4 x0 = a0[dd], x1 = a1[dd], x2 = a2[dd], x3 = a3[dd];
            acc0 += x0.x * b.x + x0.y * b.y + x0.z * b.z + x0.w * b.w;
            acc1 += x1.x * b.x + x1.y * b.y + x1.z * b.z + x1.w * b.w;
            acc2 += x2.x * b.x + x2.y * b.y + x2.z * b.z + x2.w * b.w;
            acc3 += x3.x * b.x + x3.y * b.y + x3.z * b.z + x3.w * b.w;
        }
        float sj = sq[j];
        sc[0 * NROWS + j] = sj - 2.f * acc0;
        sc[1 * NROWS + j] = sj - 2.f * acc1;
        sc[2 * NROWS + j] = sj - 2.f * acc2;
        sc[3 * NROWS + j] = sj - 2.f * acc3;
    }
    __syncthreads();
    const int w    = tid >> 6;
    const int lane = tid & 63;
    float* s = sc + w * NROWS;
    const float INF = __builtin_inff();
    float m[4]; int mi[4];
#pragma unroll
    for (int b = 0; b < 4; ++b) {
        float bm = INF; int bmi = NROWS;
        for (int t = 0; t < 32; ++t) {
            int j = lane + 64 * (b * 32 + t);
            float v = s[j];
            if (v < bm || (v == bm && j < bmi)) { bm = v; bmi = j; }
        }
        m[b] = bm; mi[b] = bmi;
    }
    const int row = r0 + w;
    for (int it = 0; it < KNN + 1; ++it) {
        float cvv = m[0]; int cii = mi[0];
#pragma unroll
        for (int b = 1; b < 4; ++b)
            if (m[b] < cvv || (m[b] == cvv && mi[b] < cii)) { cvv = m[b]; cii = mi[b]; }
        float bv = cvv; int bi = cii;
#pragma unroll
        for (int off = 32; off; off >>= 1) {
            float ov = __shfl_xor(bv, off);
            int   oi = __shfl_xor(bi, off);
            if (ov < bv || (ov == bv && oi < bi)) { bv = ov; bi = oi; }
        }
        if (it > 0 && lane == 0) knn[(size_t)row * KNN + (it - 1)] = bi;
        int ol = bi & 63;
        if (lane == ol) {
            s[bi] = INF;
            int b = (bi >> 6) >> 5;
            float bm = INF; int bmi = NROWS;
            for (int t = 0; t < 32; ++t) {
                int j = lane + 64 * (b * 32 + t);
                float v = s[j];
                if (v < bm || (v == bm && j < bmi)) { bm = v; bmi = j; }
            }
            m[b] = bm; mi[b] = bmi;
        }
    }
}

extern "C" void kernel_launch(void* const* d_in, const int* in_sizes, int n_in,
                              void* d_out, int out_size, void* d_ws, size_t ws_size,
                              hipStream_t stream) {
    const float* E     = (const float*)d_in[0];
    const float* refso = (const float*)d_in[1];
    const int*   pairs = (const int*)d_in[2];
    float* out = (float*)d_out;

    char* ws = (char*)d_ws;
    float* sq      = (float*)ws;                         // 32 KB
    float* partial = (float*)(ws + 32768);               // 8 KB
    int*   knn     = (int*)(ws + 40960);                 // 1 MB
    short* Phi     = (short*)(ws + 1089536);             // 8 MB packed hi
    short* Plo     = (short*)(ws + 9478144);             // 8 MB packed lo
    float* cval    = (float*)(ws + 17866752);            // 8*8192*33*4 = 8.65 MB
    int*   cidx    = (int*)(ws + 26517504);              // 8.65 MB
    const size_t NEED = 35168256;

    if (ws_size >= NEED) {
        hipFuncSetAttribute((const void*)distsel_k,
                            hipFuncAttributeMaxDynamicSharedMemorySize, 49152);
        sqnorm_k<<<NROWS / 4, 256, 0, stream>>>(E, sq);
        prep_k<<<NROWS * DIM / 8 / 256, 256, 0, stream>>>(E, Phi, Plo);
        distsel_k<<<(NROWS / MROWS) * STRIPS, 512, 49152, stream>>>(Phi, Plo, sq, cval, cidx);
        merge_k<<<NROWS / 4, 256, 0, stream>>>(cval, cidx, knn);
    } else {
        hipFuncSetAttribute((const void*)dist_topk_k,
                            hipFuncAttributeMaxDynamicSharedMemorySize, 131072);
        sqnorm_k<<<NROWS / 4, 256, 0, stream>>>(E, sq);
        dist_topk_k<<<NROWS / 4, 256, 131072, stream>>>(E, sq, knn);
    }
    overlap_k<<<NPAIR, 64, 0, stream>>>(knn, pairs, refso, partial);
    final_k<<<1, 256, 0, stream>>>(partial, out);
}